// Round 8
// baseline (238.562 us; speedup 1.0000x reference)
//
#include <hip/hip_runtime.h>
#include <hip/hip_bf16.h>

// Shapes (fixed by the reference)
#define NB 8
#define ND 512
#define NL 2048
#define NH 8
#define NDH 64
#define VROWS 72   // V head rows: 64 V + 1 mask row (+7 don't-care rows)

typedef __attribute__((ext_vector_type(8))) short bf16x8;
typedef __attribute__((ext_vector_type(4))) float f32x4;
typedef __attribute__((ext_vector_type(4))) unsigned int u32x4;

__device__ __forceinline__ unsigned short f2bf(float x) {
    return (unsigned short)((__float_as_uint(x) + 0x8000u) >> 16);
}

__device__ __forceinline__ float exp2_fast(float x) {
#if __has_builtin(__builtin_amdgcn_exp2f)
    return __builtin_amdgcn_exp2f(x);
#else
    return exp2f(x);
#endif
}

// pack bf16(a) | bf16(b)<<16
__device__ __forceinline__ unsigned int pack_bf16(float a, float b) {
#if __has_builtin(__builtin_amdgcn_cvt_pk_bf16_f32)
    auto r = __builtin_amdgcn_cvt_pk_bf16_f32(a, b);
    unsigned int u;
    __builtin_memcpy(&u, &r, 4);
    return u;
#else
    unsigned int ua = __float_as_uint(a) + 0x8000u;
    unsigned int ub = __float_as_uint(b) + 0x8000u;
    return __builtin_amdgcn_perm(ub, ua, 0x07060302u);
#endif
}

// async global->LDS, 16 B per lane; lds base wave-uniform, lane i -> lds+i*16.
__device__ __forceinline__ void async16(void* lds, const void* g) {
    __builtin_amdgcn_global_load_lds(
        (const __attribute__((address_space(1))) unsigned int*)g,
        (__attribute__((address_space(3))) unsigned int*)lds, 16, 0, 0);
}

// ---------------------------------------------------------------------------
// prep: fused convert_xt (blocks 0..2047) + convert_w (2048..2431) +
// V mask row (2432..2495).
// ---------------------------------------------------------------------------
__global__ __launch_bounds__(256) void prep(
    const float* __restrict__ qin,
    const float* __restrict__ w_mem, const float* __restrict__ w_q,
    const int* __restrict__ maskp,
    unsigned short* __restrict__ Xt, unsigned short* __restrict__ Wc,
    unsigned short* __restrict__ Vt)
{
    const int bid = blockIdx.x;
    const int t = threadIdx.x;
    if (bid < 2048) {
        __shared__ __align__(16) unsigned short T[64][72];
        const int l0 = (bid & 31) * 64, d0 = ((bid >> 5) & 7) * 64, b = bid >> 8;
        const float* X = qin + ((size_t)b * ND + d0) * NL + l0;
        #pragma unroll
        for (int i = 0; i < 4; ++i) {
            int e = t + i * 256;
            int d = e >> 4, l4 = (e & 15) * 4;
            float4 v = *(const float4*)(X + (size_t)d * NL + l4);
            T[l4 + 0][d] = f2bf(v.x);
            T[l4 + 1][d] = f2bf(v.y);
            T[l4 + 2][d] = f2bf(v.z);
            T[l4 + 3][d] = f2bf(v.w);
        }
        __syncthreads();
        #pragma unroll
        for (int i = 0; i < 2; ++i) {
            int e = t + i * 256;
            int row = e >> 3, c8 = (e & 7) * 8;
            *(bf16x8*)(Xt + ((size_t)b * NL + l0 + row) * ND + d0 + c8) =
                *(const bf16x8*)&T[row][c8];
        }
    } else if (bid < 2432) {
        int idx = ((bid - 2048) * 256 + t) * 8;
        int o = idx >> 9, k = idx & 511;
        const float* src;
        float sc;
        if (o < 1024) { src = w_mem + (size_t)o * ND + k; sc = 1.0f; }
        else          { src = w_q + (size_t)(o - 1024) * ND + k;
                        sc = 0.125f * 1.4426950408889634f; }
        float4 f0 = *(const float4*)src;
        float4 f1 = *(const float4*)(src + 4);
        ushort4 p0 = { f2bf(f0.x * sc), f2bf(f0.y * sc), f2bf(f0.z * sc), f2bf(f0.w * sc) };
        ushort4 p1 = { f2bf(f1.x * sc), f2bf(f1.y * sc), f2bf(f1.z * sc), f2bf(f1.w * sc) };
        *(ushort4*)(Wc + idx) = p0;
        *(ushort4*)(Wc + idx + 4) = p1;
    } else {
        const int bh = bid - 2432;
        const int b = bh >> 3;
        unsigned short* row64 = Vt + ((size_t)bh * VROWS + 64) * NL;
        for (int kk = t; kk < NL; kk += 256) {
            int s = (kk & 32) | ((kk & 12) << 1) | ((kk & 16) >> 2) | (kk & 3);
            row64[(kk & ~63) | s] =
                maskp[b * NL + kk] ? (unsigned short)0x3F80 : (unsigned short)0;
        }
    }
}

// ---------------------------------------------------------------------------
// proj_mfma: C[o][l] = sum_k Wc[o][k] * Xt[b][l][k].
// NOW double-buffered: prologue stage + ONE barrier per k-iter, DMA for
// tile t+1 in flight across the whole compute of tile t (was: issue ->
// barrier -> compute, exposing full DMA latency every iteration).
// LDS 64 KB -> 2 blocks/CU. isV hoisted out of the K-loop.
// ---------------------------------------------------------------------------
__global__ __launch_bounds__(256, 2) void proj_mfma(
    const unsigned short* __restrict__ Wc,
    const unsigned short* __restrict__ Xt,
    const int* __restrict__ maskp,
    unsigned short* __restrict__ Kh,
    unsigned short* __restrict__ Qh,
    unsigned short* __restrict__ Vt)
{
    __shared__ __align__(16) unsigned short As[2][128 * 64];
    __shared__ __align__(16) unsigned short Bs[2][128 * 64];

    const int b  = blockIdx.z;
    const int m0 = blockIdx.y * 128;
    const int n0 = blockIdx.x * 128;
    const int t  = threadIdx.x;
    const int w = t >> 6, lane = t & 63, quad = lane >> 4, lq = lane & 15;
    const int wo = (w >> 1) * 64, wl = (w & 1) * 64;
    const int lr = lane >> 3;
    const int cbsw = (lane & 7) ^ lr;
    const bool isV = (m0 >= 512) && (m0 < 1024);
    const f32x4 z4 = {0.f, 0.f, 0.f, 0.f};
    const int sw[2] = {(quad ^ (lq & 7)) * 8, ((4 + quad) ^ (lq & 7)) * 8};

    auto stageP = [&](int bi, int k0) {
        #pragma unroll 2
        for (int i = w; i < 32; i += 4) {
            if (i < 16) {
                int R = i * 8;
                async16(&As[bi][R * 64],
                        Wc + (size_t)(m0 + R + lr) * ND + k0 + cbsw * 8);
            } else {
                int R = (i - 16) * 8;
                async16(&Bs[bi][R * 64],
                        Xt + ((size_t)b * NL + n0 + R + lr) * ND + k0 + cbsw * 8);
            }
        }
    };

    f32x4 acc[4][4];
    #pragma unroll
    for (int im = 0; im < 4; ++im)
        #pragma unroll
        for (int in = 0; in < 4; ++in) acc[im][in] = z4;

    stageP(0, 0);

    if (!isV) {
        #pragma unroll 2
        for (int k0 = 0; k0 < ND; k0 += 64) {
            const int bi = (k0 >> 6) & 1;
            __syncthreads();                     // tile k0 ready
            if (k0 + 64 < ND) stageP(bi ^ 1, k0 + 64);
            #pragma unroll
            for (int ks = 0; ks < 2; ++ks) {
                bf16x8 af[4], bfr[4];
                #pragma unroll
                for (int im = 0; im < 4; ++im)
                    af[im] = *(const bf16x8*)&As[bi][(wo + im * 16 + lq) * 64 + sw[ks]];
                #pragma unroll
                for (int in = 0; in < 4; ++in)
                    bfr[in] = *(const bf16x8*)&Bs[bi][(wl + in * 16 + lq) * 64 + sw[ks]];
                #pragma unroll
                for (int im = 0; im < 4; ++im)
                    #pragma unroll
                    for (int in = 0; in < 4; ++in)
                        acc[im][in] = __builtin_amdgcn_mfma_f32_16x16x32_bf16(
                            af[im], bfr[in], acc[im][in], 0, 0, 0);
            }
        }
        unsigned short* dst = (m0 < 512) ? Kh : Qh;
        #pragma unroll
        for (int im = 0; im < 4; ++im) {
            int o  = (m0 + wo + im * 16 + quad * 4) & 511;
            int hh = o >> 6, dh = o & 63;
            #pragma unroll
            for (int in = 0; in < 4; ++in) {
                int l = n0 + wl + in * 16 + lq;
                ushort4 pk = { f2bf(acc[im][in][0]), f2bf(acc[im][in][1]),
                               f2bf(acc[im][in][2]), f2bf(acc[im][in][3]) };
                *(ushort4*)&dst[(((size_t)b * NH + hh) * NL + l) * NDH + dh] = pk;
            }
        }
    } else {
        #pragma unroll 2
        for (int k0 = 0; k0 < ND; k0 += 64) {
            const int bi = (k0 >> 6) & 1;
            __syncthreads();
            if (k0 + 64 < ND) stageP(bi ^ 1, k0 + 64);
            #pragma unroll
            for (int ks = 0; ks < 2; ++ks) {
                bf16x8 af[4], bfr[4];
                #pragma unroll
                for (int im = 0; im < 4; ++im)
                    af[im] = *(const bf16x8*)&As[bi][(wo + im * 16 + lq) * 64 + sw[ks]];
                #pragma unroll
                for (int in = 0; in < 4; ++in)
                    bfr[in] = *(const bf16x8*)&Bs[bi][(wl + in * 16 + lq) * 64 + sw[ks]];
                // swapped: acc[im = l-subtile][in = dh-subtile]
                #pragma unroll
                for (int im = 0; im < 4; ++im)
                    #pragma unroll
                    for (int in = 0; in < 4; ++in)
                        acc[im][in] = __builtin_amdgcn_mfma_f32_16x16x32_bf16(
                            bfr[im], af[in], acc[im][in], 0, 0, 0);
            }
        }
        #pragma unroll
        for (int im = 0; im < 4; ++im) {
            int l4 = n0 + wl + im * 16 + quad * 4;      // 4 consecutive l
            int kk = l4 & 63;
            int s4 = (kk & 32) | ((kk & 12) << 1) | ((kk & 16) >> 2);
            int lp = (l4 & ~63) | s4;
            int4 m4 = *(const int4*)&maskp[b * NL + l4];
            float mv[4] = {(float)m4.x, (float)m4.y, (float)m4.z, (float)m4.w};
            #pragma unroll
            for (int in = 0; in < 4; ++in) {
                int o  = m0 - 512 + wo + in * 16 + lq;  // 0..511
                int hh = o >> 6, dd = o & 63;
                ushort4 pk = { f2bf(acc[im][in][0] * mv[0]),
                               f2bf(acc[im][in][1] * mv[1]),
                               f2bf(acc[im][in][2] * mv[2]),
                               f2bf(acc[im][in][3] * mv[3]) };
                *(ushort4*)&Vt[(((size_t)(b * NH + hh)) * VROWS + dd) * NL + lp] = pk;
            }
        }
    }
}

// ---------------------------------------------------------------------------
// attn_mfma v6: software-pipelined across k-tiles to break phase-locking.
// Each body interleaves, per wave: QK(t+1) [MFMA] + exp(t) [VALU] + PV(t)
// [MFMA], so MFMA and VALU pipes are co-busy within one wave's stream.
// Quad-buffered K/V (72 KB LDS): ONE barrier per body publishes tile t+1
// and seals the t-2 buffer as the next DMA target (full-body DMA flight).
// Register-only P (key-permuted V), mask-row lsum, exp2 softmax.
// ---------------------------------------------------------------------------
__global__ __launch_bounds__(512, 4) void attn_mfma(
    const unsigned short* __restrict__ Qh,
    const unsigned short* __restrict__ Kh,
    const unsigned short* __restrict__ Vt,
    float* __restrict__ out)
{
    __shared__ __align__(16) unsigned short Ks4[4][64 * 64];  // 32 KB
    __shared__ __align__(16) unsigned short Vs4[4][80 * 64];  // 40 KB (72..79 junk)

    const int id = blockIdx.x;
    const int h  = id & 7;                 // XCD swizzle: same h -> same XCD
    const int b  = (id >> 3) & 7;
    const int q0 = (id >> 6) * 256;
    const int t = threadIdx.x;             // 0..511
    const int w = t >> 6;                  // 0..7
    const int lane = t & 63, quad = lane >> 4, lq = lane & 15;
    const int lr = lane >> 3;
    const int cbsw = (lane & 7) ^ lr;
    const f32x4 z4 = {0.f, 0.f, 0.f, 0.f};

    const unsigned short* Qg = Qh + ((size_t)(b * NH + h)) * NL * NDH;
    const unsigned short* Kg = Kh + ((size_t)(b * NH + h)) * NL * NDH;
    const unsigned short* Vg = Vt + ((size_t)(b * NH + h)) * VROWS * NL;

    const int sw0 = (quad ^ (lq & 7)) * 8;
    const int sw1 = ((4 + quad) ^ (lq & 7)) * 8;

    // wave w stages K rows 8w..8w+7 and V rows 8w..8w+7 (+ wave7: mask rows)
    const unsigned short* kgp = Kg + (size_t)(w * 8 + lr) * NDH + cbsw * 8;
    const unsigned short* vgp = Vg + (size_t)(w * 8 + lr) * NL + cbsw * 8;
    const unsigned short* vgm = Vg + (size_t)(64 + lr) * NL + cbsw * 8;

    auto stage = [&](int bi, int kn) {
        async16(&Ks4[bi][w * 512], kgp + (size_t)kn * NDH);
        async16(&Vs4[bi][w * 512], vgp + kn);
        if (w == 7) async16(&Vs4[bi][8 * 512], vgm + kn);
    };

    stage(0, 0);

    bf16x8 qf[2][2];
    #pragma unroll
    for (int ni = 0; ni < 2; ++ni)
        #pragma unroll
        for (int ks = 0; ks < 2; ++ks)
            qf[ni][ks] = *(const bf16x8*)
                &Qg[(size_t)(q0 + w * 32 + ni * 16 + lq) * NDH + ks * 32 + quad * 8];

    f32x4 oacc[5][2];
    #pragma unroll
    for (int dm = 0; dm < 5; ++dm)
        #pragma unroll
        for (int ni = 0; ni < 2; ++ni) oacc[dm][ni] = z4;

    f32x4 sA[4][2], sB[4][2];

    __syncthreads();                 // tile 0 ready (drains DMA + qf loads)
    stage(1, 64);

    // ---- QK(0) from buf 0 -> sA ----
    #pragma unroll
    for (int mi = 0; mi < 4; ++mi) {
        bf16x8 kf0 = *(const bf16x8*)&Ks4[0][(mi * 16 + lq) * 64 + sw0];
        bf16x8 kf1 = *(const bf16x8*)&Ks4[0][(mi * 16 + lq) * 64 + sw1];
        #pragma unroll
        for (int ni = 0; ni < 2; ++ni) {
            f32x4 s = __builtin_amdgcn_mfma_f32_16x16x32_bf16(kf0, qf[ni][0], z4, 0, 0, 0);
            sA[mi][ni] = __builtin_amdgcn_mfma_f32_16x16x32_bf16(kf1, qf[ni][1], s, 0, 0, 0);
        }
    }

    // body(t): barrier; stage tile t+2 into fre; interleave QK(t+1) from
    // nxt with exp(t) from SIN and PV(t) from cur.
    auto body = [&](int cur, int nxt, int fre, int kn2,
                    f32x4 (&SIN)[4][2], f32x4 (&SOUT)[4][2],
                    bool dostage, bool doqk) {
        __syncthreads();             // publishes nxt; seals fre
        if (dostage) stage(fre, kn2);
        u32x4 p0[2], p1[2];
        #pragma unroll
        for (int mi = 0; mi < 4; ++mi) {
            if (doqk) {
                bf16x8 kf0 = *(const bf16x8*)&Ks4[nxt][(mi * 16 + lq) * 64 + sw0];
                bf16x8 kf1 = *(const bf16x8*)&Ks4[nxt][(mi * 16 + lq) * 64 + sw1];
                #pragma unroll
                for (int ni = 0; ni < 2; ++ni) {
                    f32x4 s = __builtin_amdgcn_mfma_f32_16x16x32_bf16(kf0, qf[ni][0], z4, 0, 0, 0);
                    SOUT[mi][ni] = __builtin_amdgcn_mfma_f32_16x16x32_bf16(kf1, qf[ni][1], s, 0, 0, 0);
                }
            }
            const int jp = (mi & 1) * 2;
            #pragma unroll
            for (int ni = 0; ni < 2; ++ni) {
                float e0 = exp2_fast(SIN[mi][ni][0]);
                float e1 = exp2_fast(SIN[mi][ni][1]);
                float e2 = exp2_fast(SIN[mi][ni][2]);
                float e3 = exp2_fast(SIN[mi][ni][3]);
                unsigned int d0 = pack_bf16(e0, e1);
                unsigned int d1 = pack_bf16(e2, e3);
                if (mi < 2) { p0[ni][jp] = d0; p0[ni][jp + 1] = d1; }
                else        { p1[ni][jp] = d0; p1[ni][jp + 1] = d1; }
            }
            if (mi == 1) {
                #pragma unroll
                for (int dm = 0; dm < 5; ++dm) {
                    bf16x8 vf = *(const bf16x8*)&Vs4[cur][(dm * 16 + lq) * 64 + sw0];
                    oacc[dm][0] = __builtin_amdgcn_mfma_f32_16x16x32_bf16(
                        vf, __builtin_bit_cast(bf16x8, p0[0]), oacc[dm][0], 0, 0, 0);
                    oacc[dm][1] = __builtin_amdgcn_mfma_f32_16x16x32_bf16(
                        vf, __builtin_bit_cast(bf16x8, p0[1]), oacc[dm][1], 0, 0, 0);
                }
            }
            if (mi == 3) {
                #pragma unroll
                for (int dm = 0; dm < 5; ++dm) {
                    bf16x8 vf = *(const bf16x8*)&Vs4[cur][(dm * 16 + lq) * 64 + sw1];
                    oacc[dm][0] = __builtin_amdgcn_mfma_f32_16x16x32_bf16(
                        vf, __builtin_bit_cast(bf16x8, p1[0]), oacc[dm][0], 0, 0, 0);
                    oacc[dm][1] = __builtin_amdgcn_mfma_f32_16x16x32_bf16(
                        vf, __builtin_bit_cast(bf16x8, p1[1]), oacc[dm][1], 0, 0, 0);
                }
            }
        }
    };

    #pragma unroll 1
    for (int t4 = 0; t4 < 28; t4 += 4) {     // bodies t = t4 .. t4+3
        const int k = t4 * 64;
        body(0, 1, 2, k + 128, sA, sB, true, true);
        body(1, 2, 3, k + 192, sB, sA, true, true);
        body(2, 3, 0, k + 256, sA, sB, true, true);
        body(3, 0, 1, k + 320, sB, sA, true, true);
    }
    body(0, 1, 2, 30 * 64, sA, sB, true, true);    // t=28
    body(1, 2, 3, 31 * 64, sB, sA, true, true);    // t=29
    body(2, 3, 0, 0,       sA, sB, false, true);   // t=30 (QK(31), no stage)
    body(3, 0, 1, 0,       sB, sA, false, false);  // t=31 (exp/PV only)

    // ---- epilogue: lsum lives in oacc[4][ni][0] on quad-0 lanes ----
    float inv[2];
    #pragma unroll
    for (int ni = 0; ni < 2; ++ni)
        inv[ni] = 1.0f / __shfl(oacc[4][ni][0], lq);

    #pragma unroll
    for (int dm = 0; dm < 4; ++dm)
        #pragma unroll
        for (int ni = 0; ni < 2; ++ni)
            #pragma unroll
            for (int r = 0; r < 4; ++r) {
                int dh = dm * 16 + quad * 4 + r;
                int l  = q0 + w * 32 + ni * 16 + lq;
                out[((size_t)b * ND + h * NDH + dh) * NL + l] =
                    oacc[dm][ni][r] * inv[ni];
            }
}

extern "C" void kernel_launch(void* const* d_in, const int* in_sizes, int n_in,
                              void* d_out, int out_size, void* d_ws, size_t ws_size,
                              hipStream_t stream) {
    const float* queries = (const float*)d_in[0];
    const int*   maskp   = (const int*)d_in[1];
    const float* w_mem   = (const float*)d_in[2];
    const float* w_q     = (const float*)d_in[3];
    float* out = (float*)d_out;

    const size_t headElems  = (size_t)NB * NH * NL * NDH;    // 8.39M
    const size_t vElems     = (size_t)NB * NH * VROWS * NL;  // 9.44M
    unsigned short* Kh = (unsigned short*)d_ws;
    unsigned short* Vt = Kh + headElems;
    unsigned short* Qh = Vt + vElems;
    unsigned short* Wc = Qh + headElems;                     // 1536*512
    unsigned short* Xt = Wc + (size_t)1536 * ND;             // 8*2048*512
    // total ws use: ~71 MB

    prep<<<2496, 256, 0, stream>>>(queries, w_mem, w_q, maskp, Xt, Wc, Vt);

    dim3 g1(NL / 128, 1536 / 128, NB); // (16, 12, 8)
    proj_mfma<<<g1, 256, 0, stream>>>(Wc, Xt, maskp, Kh, Qh, Vt);

    attn_mfma<<<512, 512, 0, stream>>>(Qh, Kh, Vt, out);
}

// Round 9
// 209.587 us; speedup vs baseline: 1.1382x; 1.1382x over previous
//
#include <hip/hip_runtime.h>
#include <hip/hip_bf16.h>

// Shapes (fixed by the reference)
#define NB 8
#define ND 512
#define NL 2048
#define NH 8
#define NDH 64
#define VROWS 72   // V head rows: 64 V + 1 mask row (+7 don't-care rows)

typedef __attribute__((ext_vector_type(8))) short bf16x8;
typedef __attribute__((ext_vector_type(4))) float f32x4;
typedef __attribute__((ext_vector_type(4))) unsigned int u32x4;

__device__ __forceinline__ unsigned short f2bf(float x) {
    return (unsigned short)((__float_as_uint(x) + 0x8000u) >> 16);
}

__device__ __forceinline__ float exp2_fast(float x) {
#if __has_builtin(__builtin_amdgcn_exp2f)
    return __builtin_amdgcn_exp2f(x);
#else
    return exp2f(x);
#endif
}

// pack bf16(a) | bf16(b)<<16
__device__ __forceinline__ unsigned int pack_bf16(float a, float b) {
#if __has_builtin(__builtin_amdgcn_cvt_pk_bf16_f32)
    auto r = __builtin_amdgcn_cvt_pk_bf16_f32(a, b);
    unsigned int u;
    __builtin_memcpy(&u, &r, 4);
    return u;
#else
    unsigned int ua = __float_as_uint(a) + 0x8000u;
    unsigned int ub = __float_as_uint(b) + 0x8000u;
    return __builtin_amdgcn_perm(ub, ua, 0x07060302u);
#endif
}

// async global->LDS, 16 B per lane; lds base wave-uniform, lane i -> lds+i*16.
__device__ __forceinline__ void async16(void* lds, const void* g) {
    __builtin_amdgcn_global_load_lds(
        (const __attribute__((address_space(1))) unsigned int*)g,
        (__attribute__((address_space(3))) unsigned int*)lds, 16, 0, 0);
}

// ---------------------------------------------------------------------------
// prep: fused convert_xt (blocks 0..2047) + convert_w (2048..2431) +
// V mask row (2432..2495).
// ---------------------------------------------------------------------------
__global__ __launch_bounds__(256) void prep(
    const float* __restrict__ qin,
    const float* __restrict__ w_mem, const float* __restrict__ w_q,
    const int* __restrict__ maskp,
    unsigned short* __restrict__ Xt, unsigned short* __restrict__ Wc,
    unsigned short* __restrict__ Vt)
{
    const int bid = blockIdx.x;
    const int t = threadIdx.x;
    if (bid < 2048) {
        __shared__ __align__(16) unsigned short T[64][72];
        const int l0 = (bid & 31) * 64, d0 = ((bid >> 5) & 7) * 64, b = bid >> 8;
        const float* X = qin + ((size_t)b * ND + d0) * NL + l0;
        #pragma unroll
        for (int i = 0; i < 4; ++i) {
            int e = t + i * 256;
            int d = e >> 4, l4 = (e & 15) * 4;
            float4 v = *(const float4*)(X + (size_t)d * NL + l4);
            T[l4 + 0][d] = f2bf(v.x);
            T[l4 + 1][d] = f2bf(v.y);
            T[l4 + 2][d] = f2bf(v.z);
            T[l4 + 3][d] = f2bf(v.w);
        }
        __syncthreads();
        #pragma unroll
        for (int i = 0; i < 2; ++i) {
            int e = t + i * 256;
            int row = e >> 3, c8 = (e & 7) * 8;
            *(bf16x8*)(Xt + ((size_t)b * NL + l0 + row) * ND + d0 + c8) =
                *(const bf16x8*)&T[row][c8];
        }
    } else if (bid < 2432) {
        int idx = ((bid - 2048) * 256 + t) * 8;
        int o = idx >> 9, k = idx & 511;
        const float* src;
        float sc;
        if (o < 1024) { src = w_mem + (size_t)o * ND + k; sc = 1.0f; }
        else          { src = w_q + (size_t)(o - 1024) * ND + k;
                        sc = 0.125f * 1.4426950408889634f; }
        float4 f0 = *(const float4*)src;
        float4 f1 = *(const float4*)(src + 4);
        ushort4 p0 = { f2bf(f0.x * sc), f2bf(f0.y * sc), f2bf(f0.z * sc), f2bf(f0.w * sc) };
        ushort4 p1 = { f2bf(f1.x * sc), f2bf(f1.y * sc), f2bf(f1.z * sc), f2bf(f1.w * sc) };
        *(ushort4*)(Wc + idx) = p0;
        *(ushort4*)(Wc + idx + 4) = p1;
    } else {
        const int bh = bid - 2432;
        const int b = bh >> 3;
        unsigned short* row64 = Vt + ((size_t)bh * VROWS + 64) * NL;
        for (int kk = t; kk < NL; kk += 256) {
            int s = (kk & 32) | ((kk & 12) << 1) | ((kk & 16) >> 2) | (kk & 3);
            row64[(kk & ~63) | s] =
                maskp[b * NL + kk] ? (unsigned short)0x3F80 : (unsigned short)0;
        }
    }
}

// ---------------------------------------------------------------------------
// proj_mfma (R7 known-good): C[o][l] = sum_k Wc[o][k] * Xt[b][l][k].
// async global_load_lds staging, XOR-swizzled unpadded LDS (conflict-free).
// isV hoisted out of the K-loop. K/Q: ushort4 stores along dh. V: swapped
// operands -> ushort4 along l (key permutation preserves 4-contiguity),
// mask folded (masked V cols = 0).
// ---------------------------------------------------------------------------
__global__ __launch_bounds__(256, 3) void proj_mfma(
    const unsigned short* __restrict__ Wc,
    const unsigned short* __restrict__ Xt,
    const int* __restrict__ maskp,
    unsigned short* __restrict__ Kh,
    unsigned short* __restrict__ Qh,
    unsigned short* __restrict__ Vt)
{
    __shared__ __align__(16) unsigned short As[128 * 64];
    __shared__ __align__(16) unsigned short Bs[128 * 64];

    const int b  = blockIdx.z;
    const int m0 = blockIdx.y * 128;
    const int n0 = blockIdx.x * 128;
    const int t  = threadIdx.x;
    const int w = t >> 6, lane = t & 63, quad = lane >> 4, lq = lane & 15;
    const int wo = (w >> 1) * 64, wl = (w & 1) * 64;
    const int lr = lane >> 3;
    const int cbsw = (lane & 7) ^ lr;
    const bool isV = (m0 >= 512) && (m0 < 1024);
    const f32x4 z4 = {0.f, 0.f, 0.f, 0.f};
    const int sw[2] = {(quad ^ (lq & 7)) * 8, ((4 + quad) ^ (lq & 7)) * 8};

    f32x4 acc[4][4];
    #pragma unroll
    for (int im = 0; im < 4; ++im)
        #pragma unroll
        for (int in = 0; in < 4; ++in) acc[im][in] = z4;

    if (!isV) {
        for (int k0 = 0; k0 < ND; k0 += 64) {
            __syncthreads();
            #pragma unroll 2
            for (int i = w; i < 32; i += 4) {
                if (i < 16) {
                    int R = i * 8;
                    async16(&As[R * 64],
                            Wc + (size_t)(m0 + R + lr) * ND + k0 + cbsw * 8);
                } else {
                    int R = (i - 16) * 8;
                    async16(&Bs[R * 64],
                            Xt + ((size_t)b * NL + n0 + R + lr) * ND + k0 + cbsw * 8);
                }
            }
            __syncthreads();
            #pragma unroll
            for (int ks = 0; ks < 2; ++ks) {
                bf16x8 af[4], bfr[4];
                #pragma unroll
                for (int im = 0; im < 4; ++im)
                    af[im] = *(const bf16x8*)&As[(wo + im * 16 + lq) * 64 + sw[ks]];
                #pragma unroll
                for (int in = 0; in < 4; ++in)
                    bfr[in] = *(const bf16x8*)&Bs[(wl + in * 16 + lq) * 64 + sw[ks]];
                #pragma unroll
                for (int im = 0; im < 4; ++im)
                    #pragma unroll
                    for (int in = 0; in < 4; ++in)
                        acc[im][in] = __builtin_amdgcn_mfma_f32_16x16x32_bf16(
                            af[im], bfr[in], acc[im][in], 0, 0, 0);
            }
        }
        unsigned short* dst = (m0 < 512) ? Kh : Qh;
        #pragma unroll
        for (int im = 0; im < 4; ++im) {
            int o  = (m0 + wo + im * 16 + quad * 4) & 511;
            int hh = o >> 6, dh = o & 63;
            #pragma unroll
            for (int in = 0; in < 4; ++in) {
                int l = n0 + wl + in * 16 + lq;
                ushort4 pk = { f2bf(acc[im][in][0]), f2bf(acc[im][in][1]),
                               f2bf(acc[im][in][2]), f2bf(acc[im][in][3]) };
                *(ushort4*)&dst[(((size_t)b * NH + hh) * NL + l) * NDH + dh] = pk;
            }
        }
    } else {
        for (int k0 = 0; k0 < ND; k0 += 64) {
            __syncthreads();
            #pragma unroll 2
            for (int i = w; i < 32; i += 4) {
                if (i < 16) {
                    int R = i * 8;
                    async16(&As[R * 64],
                            Wc + (size_t)(m0 + R + lr) * ND + k0 + cbsw * 8);
                } else {
                    int R = (i - 16) * 8;
                    async16(&Bs[R * 64],
                            Xt + ((size_t)b * NL + n0 + R + lr) * ND + k0 + cbsw * 8);
                }
            }
            __syncthreads();
            #pragma unroll
            for (int ks = 0; ks < 2; ++ks) {
                bf16x8 af[4], bfr[4];
                #pragma unroll
                for (int im = 0; im < 4; ++im)
                    af[im] = *(const bf16x8*)&As[(wo + im * 16 + lq) * 64 + sw[ks]];
                #pragma unroll
                for (int in = 0; in < 4; ++in)
                    bfr[in] = *(const bf16x8*)&Bs[(wl + in * 16 + lq) * 64 + sw[ks]];
                // swapped: acc[im = l-subtile][in = dh-subtile]
                #pragma unroll
                for (int im = 0; im < 4; ++im)
                    #pragma unroll
                    for (int in = 0; in < 4; ++in)
                        acc[im][in] = __builtin_amdgcn_mfma_f32_16x16x32_bf16(
                            bfr[im], af[in], acc[im][in], 0, 0, 0);
            }
        }
        #pragma unroll
        for (int im = 0; im < 4; ++im) {
            int l4 = n0 + wl + im * 16 + quad * 4;      // 4 consecutive l
            int kk = l4 & 63;
            int s4 = (kk & 32) | ((kk & 12) << 1) | ((kk & 16) >> 2);
            int lp = (l4 & ~63) | s4;
            int4 m4 = *(const int4*)&maskp[b * NL + l4];
            float mv[4] = {(float)m4.x, (float)m4.y, (float)m4.z, (float)m4.w};
            #pragma unroll
            for (int in = 0; in < 4; ++in) {
                int o  = m0 - 512 + wo + in * 16 + lq;  // 0..511
                int hh = o >> 6, dd = o & 63;
                ushort4 pk = { f2bf(acc[im][in][0] * mv[0]),
                               f2bf(acc[im][in][1] * mv[1]),
                               f2bf(acc[im][in][2] * mv[2]),
                               f2bf(acc[im][in][3] * mv[3]) };
                *(ushort4*)&Vt[(((size_t)(b * NH + hh)) * VROWS + dd) * NL + lp] = pk;
            }
        }
    }
}

// ---------------------------------------------------------------------------
// attn_mfma v7: SAME per-wave structure as the 83-us R7 kernel, but
// 256-thread blocks (4 waves x 32 q-rows = 128-row q-tile), grid 1024 =
// 4 blocks/CU. The 4 waves/SIMD now come from 4 DIFFERENT blocks with
// INDEPENDENT barriers -> wave phases decorrelate, so one block's exp
// (VALU) overlaps another block's QK/PV (MFMA). (MFMA blocks its own wave
// -- intra-wave interleaving is impossible; R8's attempt spilled to
// scratch, +110 MB WRITE_SIZE.) LDS 36.9 KB/block (4x = 148 <= 160 KB).
// ---------------------------------------------------------------------------
__global__ __launch_bounds__(256, 4) void attn_mfma(
    const unsigned short* __restrict__ Qh,
    const unsigned short* __restrict__ Kh,
    const unsigned short* __restrict__ Vt,
    float* __restrict__ out)
{
    __shared__ __align__(16) unsigned short Ks2[2][64 * 64];  // 16 KB
    __shared__ __align__(16) unsigned short Vs2[2][80 * 64];  // 20 KB (72..79 junk-read)

    const int id = blockIdx.x;
    const int h  = id & 7;                 // XCD swizzle: same h -> same XCD
    const int b  = (id >> 3) & 7;
    const int q0 = (id >> 6) * 128;        // 16 q-tiles of 128 rows
    const int t = threadIdx.x;             // 0..255
    const int w = t >> 6;                  // 0..3
    const int lane = t & 63, quad = lane >> 4, lq = lane & 15;
    const int lr = lane >> 3;
    const int cbsw = (lane & 7) ^ lr;
    const f32x4 z4 = {0.f, 0.f, 0.f, 0.f};

    const unsigned short* Qg = Qh + ((size_t)(b * NH + h)) * NL * NDH;
    const unsigned short* Kg = Kh + ((size_t)(b * NH + h)) * NL * NDH;
    const unsigned short* Vg = Vt + ((size_t)(b * NH + h)) * VROWS * NL;

    const int sw0 = (quad ^ (lq & 7)) * 8;
    const int sw1 = ((4 + quad) ^ (lq & 7)) * 8;

    // staging: 17 async16 per tile (8 K-row groups, 8 V-row groups, 1 mask
    // group), distributed over 4 waves: i = w, w+4, ..., each 8 rows.
    const unsigned short* kgp = Kg + (size_t)lr * NDH + cbsw * 8;
    const unsigned short* vgp = Vg + (size_t)lr * NL + cbsw * 8;

    auto stage = [&](unsigned short* Kd, unsigned short* Vd, int kn) {
        #pragma unroll
        for (int i = w; i < 17; i += 4) {
            if (i < 8) {
                int R = i * 8;
                async16(Kd + R * 64, kgp + (size_t)(kn + R) * NDH);
            } else {
                int R = (i - 8) * 8;    // V rows R..R+7 (R=64 -> mask rows)
                async16(Vd + R * 64, vgp + (size_t)R * NL + kn);
            }
        }
    };

    // ---- stage tile 0; Q fragments straight to registers meanwhile ----
    stage(Ks2[0], Vs2[0], 0);

    bf16x8 qf[2][2];
    #pragma unroll
    for (int ni = 0; ni < 2; ++ni)
        #pragma unroll
        for (int ks = 0; ks < 2; ++ks)
            qf[ni][ks] = *(const bf16x8*)
                &Qg[(size_t)(q0 + w * 32 + ni * 16 + lq) * NDH + ks * 32 + quad * 8];

    f32x4 oacc[5][2];
    #pragma unroll
    for (int dm = 0; dm < 5; ++dm)
        #pragma unroll
        for (int ni = 0; ni < 2; ++ni) oacc[dm][ni] = z4;

    auto body = [&](const unsigned short* KsB, const unsigned short* VsB,
                    unsigned short* KsN, unsigned short* VsN,
                    int kn, bool pf) {
        __syncthreads();          // drains DMA for KsB/VsB; frees KsN/VsN
        if (pf) stage(KsN, VsN, kn);

        const unsigned short* kb0 = KsB + lq * 64 + sw0;
        const unsigned short* kb1 = KsB + lq * 64 + sw1;
        const unsigned short* vb0 = VsB + lq * 64 + sw0;
        const unsigned short* vb1 = VsB + lq * 64 + sw1;

        // ---- S^T = K Q^T (log2 units); first k-step assigns ----
        f32x4 sacc[4][2];
        #pragma unroll
        for (int mi = 0; mi < 4; ++mi) {
            bf16x8 kf = *(const bf16x8*)&kb0[mi * 1024];
            sacc[mi][0] = __builtin_amdgcn_mfma_f32_16x16x32_bf16(kf, qf[0][0], z4, 0, 0, 0);
            sacc[mi][1] = __builtin_amdgcn_mfma_f32_16x16x32_bf16(kf, qf[1][0], z4, 0, 0, 0);
        }
        #pragma unroll
        for (int mi = 0; mi < 4; ++mi) {
            bf16x8 kf = *(const bf16x8*)&kb1[mi * 1024];
            sacc[mi][0] = __builtin_amdgcn_mfma_f32_16x16x32_bf16(kf, qf[0][1], sacc[mi][0], 0, 0, 0);
            sacc[mi][1] = __builtin_amdgcn_mfma_f32_16x16x32_bf16(kf, qf[1][1], sacc[mi][1], 0, 0, 0);
        }

        // ---- per ks-half: p = exp2(s), pack, PV MFMA ----
        #pragma unroll
        for (int ks = 0; ks < 2; ++ks) {
            u32x4 pfu[2];
            #pragma unroll
            for (int half = 0; half < 2; ++half) {
                const int mi = ks * 2 + half, jp = half * 2;
                #pragma unroll
                for (int ni = 0; ni < 2; ++ni) {
                    float e0 = exp2_fast(sacc[mi][ni][0]);
                    float e1 = exp2_fast(sacc[mi][ni][1]);
                    float e2 = exp2_fast(sacc[mi][ni][2]);
                    float e3 = exp2_fast(sacc[mi][ni][3]);
                    pfu[ni][jp + 0] = pack_bf16(e0, e1);
                    pfu[ni][jp + 1] = pack_bf16(e2, e3);
                }
            }
            const unsigned short* vb = ks ? vb1 : vb0;
            #pragma unroll
            for (int dm = 0; dm < 5; ++dm) {
                bf16x8 vf = *(const bf16x8*)&vb[dm * 1024];
                oacc[dm][0] = __builtin_amdgcn_mfma_f32_16x16x32_bf16(
                    vf, __builtin_bit_cast(bf16x8, pfu[0]), oacc[dm][0], 0, 0, 0);
                oacc[dm][1] = __builtin_amdgcn_mfma_f32_16x16x32_bf16(
                    vf, __builtin_bit_cast(bf16x8, pfu[1]), oacc[dm][1], 0, 0, 0);
            }
        }
    };

    for (int k0 = 0; k0 < NL; k0 += 128) {
        body(Ks2[0], Vs2[0], Ks2[1], Vs2[1], k0 + 64, true);
        body(Ks2[1], Vs2[1], Ks2[0], Vs2[0], k0 + 128, k0 + 128 < NL);
    }

    // ---- epilogue: lsum lives in oacc[4][ni][0] on quad-0 lanes ----
    float inv[2];
    #pragma unroll
    for (int ni = 0; ni < 2; ++ni)
        inv[ni] = 1.0f / __shfl(oacc[4][ni][0], lq);

    #pragma unroll
    for (int dm = 0; dm < 4; ++dm)
        #pragma unroll
        for (int ni = 0; ni < 2; ++ni)
            #pragma unroll
            for (int r = 0; r < 4; ++r) {
                int dh = dm * 16 + quad * 4 + r;
                int l  = q0 + w * 32 + ni * 16 + lq;
                out[((size_t)b * ND + h * NDH + dh) * NL + l] =
                    oacc[dm][ni][r] * inv[ni];
            }
}

extern "C" void kernel_launch(void* const* d_in, const int* in_sizes, int n_in,
                              void* d_out, int out_size, void* d_ws, size_t ws_size,
                              hipStream_t stream) {
    const float* queries = (const float*)d_in[0];
    const int*   maskp   = (const int*)d_in[1];
    const float* w_mem   = (const float*)d_in[2];
    const float* w_q     = (const float*)d_in[3];
    float* out = (float*)d_out;

    const size_t headElems  = (size_t)NB * NH * NL * NDH;    // 8.39M
    const size_t vElems     = (size_t)NB * NH * VROWS * NL;  // 9.44M
    unsigned short* Kh = (unsigned short*)d_ws;
    unsigned short* Vt = Kh + headElems;
    unsigned short* Qh = Vt + vElems;
    unsigned short* Wc = Qh + headElems;                     // 1536*512
    unsigned short* Xt = Wc + (size_t)1536 * ND;             // 8*2048*512
    // total ws use: ~71 MB

    prep<<<2496, 256, 0, stream>>>(queries, w_mem, w_q, maskp, Xt, Wc, Vt);

    dim3 g1(NL / 128, 1536 / 128, NB); // (16, 12, 8)
    proj_mfma<<<g1, 256, 0, stream>>>(Wc, Xt, maskp, Kh, Qh, Vt);

    attn_mfma<<<1024, 256, 0, stream>>>(Qh, Kh, Vt, out);
}

// Round 10
// 184.179 us; speedup vs baseline: 1.2953x; 1.1380x over previous
//
#include <hip/hip_runtime.h>
#include <hip/hip_bf16.h>

// Shapes (fixed by the reference)
#define NB 8
#define ND 512
#define NL 2048
#define NH 8
#define NDH 64
#define VROWS 72   // V head rows: 64 V + 1 mask row (+7 don't-care rows)

typedef __attribute__((ext_vector_type(8))) short bf16x8;
typedef __attribute__((ext_vector_type(4))) float f32x4;
typedef __attribute__((ext_vector_type(4))) unsigned int u32x4;

__device__ __forceinline__ unsigned short f2bf(float x) {
    return (unsigned short)((__float_as_uint(x) + 0x8000u) >> 16);
}

__device__ __forceinline__ float exp2_fast(float x) {
#if __has_builtin(__builtin_amdgcn_exp2f)
    return __builtin_amdgcn_exp2f(x);
#else
    return exp2f(x);
#endif
}

// pack bf16(a) | bf16(b)<<16
__device__ __forceinline__ unsigned int pack_bf16(float a, float b) {
#if __has_builtin(__builtin_amdgcn_cvt_pk_bf16_f32)
    auto r = __builtin_amdgcn_cvt_pk_bf16_f32(a, b);
    unsigned int u;
    __builtin_memcpy(&u, &r, 4);
    return u;
#else
    unsigned int ua = __float_as_uint(a) + 0x8000u;
    unsigned int ub = __float_as_uint(b) + 0x8000u;
    return __builtin_amdgcn_perm(ub, ua, 0x07060302u);
#endif
}

// key permutation within a 64-tile (PV B-operand == S^T C-layout)
__device__ __forceinline__ int perm64(int k) {
    return (k & 32) | ((k & 12) << 1) | ((k & 16) >> 2) | (k & 3);
}

// async global->LDS, 16 B per lane; lds base wave-uniform, lane i -> lds+i*16.
__device__ __forceinline__ void async16(void* lds, const void* g) {
    __builtin_amdgcn_global_load_lds(
        (const __attribute__((address_space(1))) unsigned int*)g,
        (__attribute__((address_space(3))) unsigned int*)lds, 16, 0, 0);
}

// ---------------------------------------------------------------------------
// prep: fused convert_xt (blocks 0..2047) + convert_w (2048..2431) +
// per-batch mask compaction scan (2432..2439).
// Scan block b: cmap[b][l] = compacted index j (or -1 if masked), ntile[b] =
// ceil(n_b/64); writes the key-permuted mask row (1 for j<n_b, 0 for pad)
// and ZEROES the K-rows / V-cols of the padding slots for all 8 heads.
// Masked keys are thereby removed from attention entirely (exact: their
// softmax weight is exp(-1e30) = 0).
// ---------------------------------------------------------------------------
__global__ __launch_bounds__(256) void prep(
    const float* __restrict__ qin,
    const float* __restrict__ w_mem, const float* __restrict__ w_q,
    const int* __restrict__ maskp,
    unsigned short* __restrict__ Xt, unsigned short* __restrict__ Wc,
    unsigned short* __restrict__ Vt, unsigned short* __restrict__ Kh,
    int* __restrict__ cmap, int* __restrict__ ntile)
{
    const int bid = blockIdx.x;
    const int t = threadIdx.x;
    if (bid < 2048) {
        __shared__ __align__(16) unsigned short T[64][72];
        const int l0 = (bid & 31) * 64, d0 = ((bid >> 5) & 7) * 64, b = bid >> 8;
        const float* X = qin + ((size_t)b * ND + d0) * NL + l0;
        #pragma unroll
        for (int i = 0; i < 4; ++i) {
            int e = t + i * 256;
            int d = e >> 4, l4 = (e & 15) * 4;
            float4 v = *(const float4*)(X + (size_t)d * NL + l4);
            T[l4 + 0][d] = f2bf(v.x);
            T[l4 + 1][d] = f2bf(v.y);
            T[l4 + 2][d] = f2bf(v.z);
            T[l4 + 3][d] = f2bf(v.w);
        }
        __syncthreads();
        #pragma unroll
        for (int i = 0; i < 2; ++i) {
            int e = t + i * 256;
            int row = e >> 3, c8 = (e & 7) * 8;
            *(bf16x8*)(Xt + ((size_t)b * NL + l0 + row) * ND + d0 + c8) =
                *(const bf16x8*)&T[row][c8];
        }
    } else if (bid < 2432) {
        int idx = ((bid - 2048) * 256 + t) * 8;
        int o = idx >> 9, k = idx & 511;
        const float* src;
        float sc;
        if (o < 1024) { src = w_mem + (size_t)o * ND + k; sc = 1.0f; }
        else          { src = w_q + (size_t)(o - 1024) * ND + k;
                        sc = 0.125f * 1.4426950408889634f; }
        float4 f0 = *(const float4*)src;
        float4 f1 = *(const float4*)(src + 4);
        ushort4 p0 = { f2bf(f0.x * sc), f2bf(f0.y * sc), f2bf(f0.z * sc), f2bf(f0.w * sc) };
        ushort4 p1 = { f2bf(f1.x * sc), f2bf(f1.y * sc), f2bf(f1.z * sc), f2bf(f1.w * sc) };
        *(ushort4*)(Wc + idx) = p0;
        *(ushort4*)(Wc + idx + 4) = p1;
    } else {
        // ---- per-batch mask compaction ----
        __shared__ int wsum[4];
        const int b = bid - 2432;
        const int lane = t & 63, wv = t >> 6;
        int4 ma = *(const int4*)&maskp[b * NL + t * 8];
        int4 mb = *(const int4*)&maskp[b * NL + t * 8 + 4];
        int m[8] = {ma.x, ma.y, ma.z, ma.w, mb.x, mb.y, mb.z, mb.w};
        int loc = 0;
        #pragma unroll
        for (int i = 0; i < 8; ++i) loc += m[i];
        int sc = loc;                         // wave inclusive scan
        #pragma unroll
        for (int off = 1; off < 64; off <<= 1) {
            int v = __shfl_up(sc, off);
            if (lane >= off) sc += v;
        }
        if (lane == 63) wsum[wv] = sc;
        __syncthreads();
        int wbase = 0;
        #pragma unroll
        for (int i = 0; i < 4; ++i) if (i < wv) wbase += wsum[i];
        int j = wbase + sc - loc;             // exclusive prefix for this group
        #pragma unroll
        for (int i = 0; i < 8; ++i) {
            cmap[b * NL + t * 8 + i] = m[i] ? j : -1;
            j += m[i];
        }
        const int nb = wsum[0] + wsum[1] + wsum[2] + wsum[3];
        const int Nt = (nb + 63) & ~63;
        if (t == 0) ntile[b] = Nt >> 6;
        const int pad = Nt - nb;
        for (int h = 0; h < NH; ++h) {
            unsigned short* row64 = Vt + (((size_t)(b * NH + h)) * VROWS + 64) * NL;
            for (int jj = t; jj < Nt; jj += 256)
                row64[(jj & ~63) | perm64(jj & 63)] =
                    (jj < nb) ? (unsigned short)0x3F80 : (unsigned short)0;
            for (int e = t; e < pad * 64; e += 256) {
                int jj = nb + (e >> 6), dd = e & 63;
                int slot = (jj & ~63) | perm64(jj & 63);
                Vt[(((size_t)(b * NH + h)) * VROWS + dd) * NL + slot] = 0;
                Kh[(((size_t)(b * NH + h)) * NL + jj) * NDH + dd] = 0;
            }
        }
    }
}

// ---------------------------------------------------------------------------
// proj_mfma: C[o][l] = sum_k Wc[o][k] * Xt[b][l][k].
// async global_load_lds staging, XOR-swizzled unpadded LDS (conflict-free).
// K region: store at COMPACTED row j = cmap[l] (ushort4 along dh; masked
// keys dropped). Q: unchanged. V region: swapped operands, scalar b16
// scatter to compacted+permuted columns (masked keys dropped).
// ---------------------------------------------------------------------------
__global__ __launch_bounds__(256, 3) void proj_mfma(
    const unsigned short* __restrict__ Wc,
    const unsigned short* __restrict__ Xt,
    const int* __restrict__ cmap,
    unsigned short* __restrict__ Kh,
    unsigned short* __restrict__ Qh,
    unsigned short* __restrict__ Vt)
{
    __shared__ __align__(16) unsigned short As[128 * 64];
    __shared__ __align__(16) unsigned short Bs[128 * 64];

    const int b  = blockIdx.z;
    const int m0 = blockIdx.y * 128;
    const int n0 = blockIdx.x * 128;
    const int t  = threadIdx.x;
    const int w = t >> 6, lane = t & 63, quad = lane >> 4, lq = lane & 15;
    const int wo = (w >> 1) * 64, wl = (w & 1) * 64;
    const int lr = lane >> 3;
    const int cbsw = (lane & 7) ^ lr;
    const bool isV = (m0 >= 512) && (m0 < 1024);
    const f32x4 z4 = {0.f, 0.f, 0.f, 0.f};
    const int sw[2] = {(quad ^ (lq & 7)) * 8, ((4 + quad) ^ (lq & 7)) * 8};

    f32x4 acc[4][4];
    #pragma unroll
    for (int im = 0; im < 4; ++im)
        #pragma unroll
        for (int in = 0; in < 4; ++in) acc[im][in] = z4;

    if (!isV) {
        for (int k0 = 0; k0 < ND; k0 += 64) {
            __syncthreads();
            #pragma unroll 2
            for (int i = w; i < 32; i += 4) {
                if (i < 16) {
                    int R = i * 8;
                    async16(&As[R * 64],
                            Wc + (size_t)(m0 + R + lr) * ND + k0 + cbsw * 8);
                } else {
                    int R = (i - 16) * 8;
                    async16(&Bs[R * 64],
                            Xt + ((size_t)b * NL + n0 + R + lr) * ND + k0 + cbsw * 8);
                }
            }
            __syncthreads();
            #pragma unroll
            for (int ks = 0; ks < 2; ++ks) {
                bf16x8 af[4], bfr[4];
                #pragma unroll
                for (int im = 0; im < 4; ++im)
                    af[im] = *(const bf16x8*)&As[(wo + im * 16 + lq) * 64 + sw[ks]];
                #pragma unroll
                for (int in = 0; in < 4; ++in)
                    bfr[in] = *(const bf16x8*)&Bs[(wl + in * 16 + lq) * 64 + sw[ks]];
                #pragma unroll
                for (int im = 0; im < 4; ++im)
                    #pragma unroll
                    for (int in = 0; in < 4; ++in)
                        acc[im][in] = __builtin_amdgcn_mfma_f32_16x16x32_bf16(
                            af[im], bfr[in], acc[im][in], 0, 0, 0);
            }
        }
        if (m0 < 512) {
            // K region: compacted rows
            int j[4];
            #pragma unroll
            for (int in = 0; in < 4; ++in)
                j[in] = cmap[b * NL + n0 + wl + in * 16 + lq];
            #pragma unroll
            for (int im = 0; im < 4; ++im) {
                int o  = (m0 + wo + im * 16 + quad * 4) & 511;
                int hh = o >> 6, dh = o & 63;
                #pragma unroll
                for (int in = 0; in < 4; ++in) {
                    if (j[in] >= 0) {
                        ushort4 pk = { f2bf(acc[im][in][0]), f2bf(acc[im][in][1]),
                                       f2bf(acc[im][in][2]), f2bf(acc[im][in][3]) };
                        *(ushort4*)&Kh[(((size_t)b * NH + hh) * NL + j[in]) * NDH + dh] = pk;
                    }
                }
            }
        } else {
            // Q region: unchanged
            #pragma unroll
            for (int im = 0; im < 4; ++im) {
                int o  = (m0 + wo + im * 16 + quad * 4) & 511;
                int hh = o >> 6, dh = o & 63;
                #pragma unroll
                for (int in = 0; in < 4; ++in) {
                    int l = n0 + wl + in * 16 + lq;
                    ushort4 pk = { f2bf(acc[im][in][0]), f2bf(acc[im][in][1]),
                                   f2bf(acc[im][in][2]), f2bf(acc[im][in][3]) };
                    *(ushort4*)&Qh[(((size_t)b * NH + hh) * NL + l) * NDH + dh] = pk;
                }
            }
        }
    } else {
        for (int k0 = 0; k0 < ND; k0 += 64) {
            __syncthreads();
            #pragma unroll 2
            for (int i = w; i < 32; i += 4) {
                if (i < 16) {
                    int R = i * 8;
                    async16(&As[R * 64],
                            Wc + (size_t)(m0 + R + lr) * ND + k0 + cbsw * 8);
                } else {
                    int R = (i - 16) * 8;
                    async16(&Bs[R * 64],
                            Xt + ((size_t)b * NL + n0 + R + lr) * ND + k0 + cbsw * 8);
                }
            }
            __syncthreads();
            #pragma unroll
            for (int ks = 0; ks < 2; ++ks) {
                bf16x8 af[4], bfr[4];
                #pragma unroll
                for (int im = 0; im < 4; ++im)
                    af[im] = *(const bf16x8*)&As[(wo + im * 16 + lq) * 64 + sw[ks]];
                #pragma unroll
                for (int in = 0; in < 4; ++in)
                    bfr[in] = *(const bf16x8*)&Bs[(wl + in * 16 + lq) * 64 + sw[ks]];
                // swapped: acc[im = l-subtile][in = dh-subtile]
                #pragma unroll
                for (int im = 0; im < 4; ++im)
                    #pragma unroll
                    for (int in = 0; in < 4; ++in)
                        acc[im][in] = __builtin_amdgcn_mfma_f32_16x16x32_bf16(
                            bfr[im], af[in], acc[im][in], 0, 0, 0);
            }
        }
        // V region: compacted + key-permuted scalar scatter
        #pragma unroll
        for (int im = 0; im < 4; ++im) {
            int l4 = n0 + wl + im * 16 + quad * 4;      // 4 consecutive l
            int4 j4 = *(const int4*)&cmap[b * NL + l4];
            int jj[4] = {j4.x, j4.y, j4.z, j4.w};
            int slot[4];
            #pragma unroll
            for (int r = 0; r < 4; ++r)
                slot[r] = (jj[r] & ~63) | perm64(jj[r] & 63);
            #pragma unroll
            for (int in = 0; in < 4; ++in) {
                int o  = m0 - 512 + wo + in * 16 + lq;  // 0..511
                int hh = o >> 6, dd = o & 63;
                const size_t rowbase = (((size_t)(b * NH + hh)) * VROWS + dd) * NL;
                #pragma unroll
                for (int r = 0; r < 4; ++r)
                    if (jj[r] >= 0)
                        Vt[rowbase + slot[r]] = f2bf(acc[im][in][r]);
            }
        }
    }
}

// ---------------------------------------------------------------------------
// attn_mfma (R7 structure + compacted keys): 512-thread blocks (8 waves x
// 32 q-rows = 256-row q-tile), grid 512 = 2 blocks/CU. Double-buffered
// async K/V staging, register-only P (key-permuted V), mask-row lsum,
// exp2 softmax. K-loop runs over ntile[b] COMPACTED tiles (~16 vs 32):
// masked keys are gone, halving MFMA + exp + LDS + staging work.
// ---------------------------------------------------------------------------
__global__ __launch_bounds__(512, 4) void attn_mfma(
    const unsigned short* __restrict__ Qh,
    const unsigned short* __restrict__ Kh,
    const unsigned short* __restrict__ Vt,
    const int* __restrict__ ntilep,
    float* __restrict__ out)
{
    __shared__ __align__(16) unsigned short Ks2[2][64 * 64];  // 16 KB
    __shared__ __align__(16) unsigned short Vs2[2][80 * 64];  // 20 KB

    const int id = blockIdx.x;
    const int h  = id & 7;                 // XCD swizzle: same h -> same XCD
    const int b  = (id >> 3) & 7;
    const int q0 = (id >> 6) * 256;
    const int t = threadIdx.x;             // 0..511
    const int w = t >> 6;                  // 0..7
    const int lane = t & 63, quad = lane >> 4, lq = lane & 15;
    const int lr = lane >> 3;
    const int cbsw = (lane & 7) ^ lr;
    const f32x4 z4 = {0.f, 0.f, 0.f, 0.f};

    const unsigned short* Qg = Qh + ((size_t)(b * NH + h)) * NL * NDH;
    const unsigned short* Kg = Kh + ((size_t)(b * NH + h)) * NL * NDH;
    const unsigned short* Vg = Vt + ((size_t)(b * NH + h)) * VROWS * NL;
    const int ntiles = ntilep[b];

    const int sw0 = (quad ^ (lq & 7)) * 8;
    const int sw1 = ((4 + quad) ^ (lq & 7)) * 8;

    // wave w stages K rows 8w..8w+7 and V rows 8w..8w+7 (+ wave7: mask rows)
    const unsigned short* kgp = Kg + (size_t)(w * 8 + lr) * NDH + cbsw * 8;
    const unsigned short* vgp = Vg + (size_t)(w * 8 + lr) * NL + cbsw * 8;
    const unsigned short* vgm = Vg + (size_t)(64 + lr) * NL + cbsw * 8;

    auto stage = [&](unsigned short* Kd, unsigned short* Vd, int kn) {
        async16(Kd + w * 512, kgp + (size_t)kn * NDH);
        async16(Vd + w * 512, vgp + kn);
        if (w == 7) async16(Vd + 8 * 512, vgm + kn);
    };

    // ---- stage tile 0; Q fragments straight to registers meanwhile ----
    stage(Ks2[0], Vs2[0], 0);

    bf16x8 qf[2][2];
    #pragma unroll
    for (int ni = 0; ni < 2; ++ni)
        #pragma unroll
        for (int ks = 0; ks < 2; ++ks)
            qf[ni][ks] = *(const bf16x8*)
                &Qg[(size_t)(q0 + w * 32 + ni * 16 + lq) * NDH + ks * 32 + quad * 8];

    f32x4 oacc[5][2];
    #pragma unroll
    for (int dm = 0; dm < 5; ++dm)
        #pragma unroll
        for (int ni = 0; ni < 2; ++ni) oacc[dm][ni] = z4;

    auto body = [&](const unsigned short* KsB, const unsigned short* VsB,
                    unsigned short* KsN, unsigned short* VsN,
                    int kn, bool pf) {
        __syncthreads();          // drains DMA for KsB/VsB; frees KsN/VsN
        if (pf) stage(KsN, VsN, kn);

        const unsigned short* kb0 = KsB + lq * 64 + sw0;
        const unsigned short* kb1 = KsB + lq * 64 + sw1;
        const unsigned short* vb0 = VsB + lq * 64 + sw0;
        const unsigned short* vb1 = VsB + lq * 64 + sw1;

        // ---- S^T = K Q^T (log2 units); first k-step assigns ----
        f32x4 sacc[4][2];
        #pragma unroll
        for (int mi = 0; mi < 4; ++mi) {
            bf16x8 kf = *(const bf16x8*)&kb0[mi * 1024];
            sacc[mi][0] = __builtin_amdgcn_mfma_f32_16x16x32_bf16(kf, qf[0][0], z4, 0, 0, 0);
            sacc[mi][1] = __builtin_amdgcn_mfma_f32_16x16x32_bf16(kf, qf[1][0], z4, 0, 0, 0);
        }
        #pragma unroll
        for (int mi = 0; mi < 4; ++mi) {
            bf16x8 kf = *(const bf16x8*)&kb1[mi * 1024];
            sacc[mi][0] = __builtin_amdgcn_mfma_f32_16x16x32_bf16(kf, qf[0][1], sacc[mi][0], 0, 0, 0);
            sacc[mi][1] = __builtin_amdgcn_mfma_f32_16x16x32_bf16(kf, qf[1][1], sacc[mi][1], 0, 0, 0);
        }

        // ---- per ks-half: p = exp2(s), pack, PV MFMA ----
        #pragma unroll
        for (int ks = 0; ks < 2; ++ks) {
            u32x4 pfu[2];
            #pragma unroll
            for (int half = 0; half < 2; ++half) {
                const int mi = ks * 2 + half, jp = half * 2;
                #pragma unroll
                for (int ni = 0; ni < 2; ++ni) {
                    float e0 = exp2_fast(sacc[mi][ni][0]);
                    float e1 = exp2_fast(sacc[mi][ni][1]);
                    float e2 = exp2_fast(sacc[mi][ni][2]);
                    float e3 = exp2_fast(sacc[mi][ni][3]);
                    pfu[ni][jp + 0] = pack_bf16(e0, e1);
                    pfu[ni][jp + 1] = pack_bf16(e2, e3);
                }
            }
            const unsigned short* vb = ks ? vb1 : vb0;
            #pragma unroll
            for (int dm = 0; dm < 5; ++dm) {
                bf16x8 vf = *(const bf16x8*)&vb[dm * 1024];
                oacc[dm][0] = __builtin_amdgcn_mfma_f32_16x16x32_bf16(
                    vf, __builtin_bit_cast(bf16x8, pfu[0]), oacc[dm][0], 0, 0, 0);
                oacc[dm][1] = __builtin_amdgcn_mfma_f32_16x16x32_bf16(
                    vf, __builtin_bit_cast(bf16x8, pfu[1]), oacc[dm][1], 0, 0, 0);
            }
        }
    };

    int kt = 0;
    #pragma unroll 1
    for (; kt + 2 <= ntiles; kt += 2) {
        body(Ks2[0], Vs2[0], Ks2[1], Vs2[1], (kt + 1) * 64, true);
        body(Ks2[1], Vs2[1], Ks2[0], Vs2[0], (kt + 2) * 64, kt + 2 < ntiles);
    }
    if (kt < ntiles)   // odd tail: tile kt is staged in buffer 0
        body(Ks2[0], Vs2[0], Ks2[1], Vs2[1], 0, false);

    // ---- epilogue: lsum lives in oacc[4][ni][0] on quad-0 lanes ----
    float inv[2];
    #pragma unroll
    for (int ni = 0; ni < 2; ++ni)
        inv[ni] = 1.0f / __shfl(oacc[4][ni][0], lq);

    #pragma unroll
    for (int dm = 0; dm < 4; ++dm)
        #pragma unroll
        for (int ni = 0; ni < 2; ++ni)
            #pragma unroll
            for (int r = 0; r < 4; ++r) {
                int dh = dm * 16 + quad * 4 + r;
                int l  = q0 + w * 32 + ni * 16 + lq;
                out[((size_t)b * ND + h * NDH + dh) * NL + l] =
                    oacc[dm][ni][r] * inv[ni];
            }
}

extern "C" void kernel_launch(void* const* d_in, const int* in_sizes, int n_in,
                              void* d_out, int out_size, void* d_ws, size_t ws_size,
                              hipStream_t stream) {
    const float* queries = (const float*)d_in[0];
    const int*   maskp   = (const int*)d_in[1];
    const float* w_mem   = (const float*)d_in[2];
    const float* w_q     = (const float*)d_in[3];
    float* out = (float*)d_out;

    const size_t headElems  = (size_t)NB * NH * NL * NDH;    // 8.39M
    const size_t vElems     = (size_t)NB * NH * VROWS * NL;  // 9.44M
    unsigned short* Kh = (unsigned short*)d_ws;
    unsigned short* Vt = Kh + headElems;
    unsigned short* Qh = Vt + vElems;
    unsigned short* Wc = Qh + headElems;                     // 1536*512
    unsigned short* Xt = Wc + (size_t)1536 * ND;             // 8*2048*512
    int* cmap  = (int*)(Xt + (size_t)NB * NL * ND);          // 8*2048 ints
    int* ntile = cmap + NB * NL;                             // 8 ints
    // total ws use: ~71 MB

    prep<<<2440, 256, 0, stream>>>(queries, w_mem, w_q, maskp,
                                   Xt, Wc, Vt, Kh, cmap, ntile);

    dim3 g1(NL / 128, 1536 / 128, NB); // (16, 12, 8)
    proj_mfma<<<g1, 256, 0, stream>>>(Wc, Xt, cmap, Kh, Qh, Vt);

    attn_mfma<<<512, 512, 0, stream>>>(Qh, Kh, Vt, ntile, out);
}